// Round 14
// baseline (1594.447 us; speedup 1.0000x reference)
//
#include <hip/hip_runtime.h>
#include <hip/hip_bf16.h>

constexpr int CB = 64;     // batch
constexpr int CS = 512;    // seq
constexpr int CDE = 384;   // embed dim
constexpr int CD = 1024;   // model dim
constexpr int CM = 16;     // hist depth
constexpr int CH = 4;      // neuron hidden
constexpr int CNH = 8;     // heads
constexpr int CDH = 128;   // head dim
constexpr int CDA = 512;
constexpr int CDO = 512;
constexpr int CT = 16;     // T_MAX
constexpr int CTP1 = 17;

typedef __attribute__((ext_vector_type(8))) short bfrag;   // 8 bf16 (4 VGPRs)
typedef __attribute__((ext_vector_type(4))) float ffrag;   // MFMA accumulator

__device__ __forceinline__ float gelu_exact(float x) {
    return 0.5f * x * (1.0f + erff(x * 0.70710678118654752440f));
}
__device__ __forceinline__ float softplusf(float x) {
    return fmaxf(x, 0.0f) + log1pf(expf(-fabsf(x)));
}
__device__ __forceinline__ float us2f(unsigned short u) {
    union { unsigned int i; float f; } c; c.i = ((unsigned int)u) << 16; return c.f;
}
__device__ __forceinline__ unsigned short f2us(float x) {
    __hip_bfloat16 b = __float2bfloat16(x);  // RNE
    union { __hip_bfloat16 b; unsigned short u; } c; c.b = b; return c.u;
}

template <typename T>
__device__ __forceinline__ float4 ld4(const T* p);
template <>
__device__ __forceinline__ float4 ld4<float>(const float* p) { return *(const float4*)p; }
template <>
__device__ __forceinline__ float4 ld4<unsigned short>(const unsigned short* p) {
    ushort4 u = *(const ushort4*)p;
    return make_float4(us2f(u.x), us2f(u.y), us2f(u.z), us2f(u.w));
}
__device__ __forceinline__ void st4(float* p, float4 v) { *(float4*)p = v; }
__device__ __forceinline__ void st4(unsigned short* p, float4 v) {
    ushort4 u = make_ushort4(f2us(v.x), f2us(v.y), f2us(v.z), f2us(v.w));
    *(ushort4*)p = u;
}

__device__ __forceinline__ bfrag ld8bf(const unsigned short* p) {
    return *(const bfrag*)p;
}
__device__ __forceinline__ bfrag ld8bf(const float* p) {
    float4 a = *(const float4*)p;
    float4 b = *(const float4*)(p + 4);
    bfrag v;
    v[0] = (short)f2us(a.x); v[1] = (short)f2us(a.y);
    v[2] = (short)f2us(a.z); v[3] = (short)f2us(a.w);
    v[4] = (short)f2us(b.x); v[5] = (short)f2us(b.y);
    v[6] = (short)f2us(b.z); v[7] = (short)f2us(b.w);
    return v;
}

// async global->LDS, 16B per lane; LDS dest = wave-uniform base + lane*16
__device__ __forceinline__ void gload_lds16(const unsigned short* g, char* lds) {
    __builtin_amdgcn_global_load_lds(
        (const __attribute__((address_space(1))) unsigned int*)g,
        (__attribute__((address_space(3))) unsigned int*)lds, 16, 0, 0);
}

// fp32 -> bf16 bulk convert (n divisible by 4)
__global__ __launch_bounds__(256) void convert_bf16_kernel(
    const float* __restrict__ src, unsigned short* __restrict__ dst, int n4) {
    int i = blockIdx.x * 256 + threadIdx.x;
    if (i < n4) {
        float4 v = *(const float4*)(src + (size_t)i * 4);
        st4(dst + (size_t)i * 4, v);
    }
}

// WqT[a][d] = Wq[d][a] (bf16); Wq is [CD][CDA]
__global__ __launch_bounds__(256) void transpose_wq_kernel(
    const float* __restrict__ Wq, unsigned short* __restrict__ WqT) {
    int i = blockIdx.x * 256 + threadIdx.x;
    if (i < CDA * CD) {
        int a = i / CD, d = i - a * CD;
        WqT[i] = f2us(Wq[(size_t)d * CDA + a]);
    }
}

// woT[d][k] = Wo[k][d] (bf16); Wo is [CD][CD]
__global__ __launch_bounds__(256) void transpose_wo_kernel(
    const float* __restrict__ Wo, unsigned short* __restrict__ WoT) {
    int i = blockIdx.x * 256 + threadIdx.x;
    if (i < CD * CD) {
        int d = i >> 10, k = i & 1023;
        WoT[i] = f2us(Wo[(size_t)k * CD + d]);
    }
}

// Split Ws1 into packed bf16 halves ws1a (cols 0..1023), ws1b (1024..2047)
__global__ __launch_bounds__(256) void pack_ws1_kernel(
    const float* __restrict__ Ws1, unsigned short* __restrict__ ws1a,
    unsigned short* __restrict__ ws1b) {
    int i = blockIdx.x * 256 + threadIdx.x;
    if (i < 2 * CD * CD) {
        int j = i >> 10, k = i & 1023;
        ws1a[i] = f2us(Ws1[(size_t)j * (2 * CD) + k]);
        ws1b[i] = f2us(Ws1[(size_t)j * (2 * CD) + CD + k]);
    }
}

// beff[i] = bq3[i] + sum_d Wq3[i,d]*bq[d]
__global__ __launch_bounds__(256) void beff_kernel(
    const float* __restrict__ Wqkv, const float* __restrict__ bq,
    const float* __restrict__ bqkv, float* __restrict__ beff) {
    int i = blockIdx.x * 256 + threadIdx.x;
    if (i < CD) {
        const float* w = Wqkv + (size_t)i * CD;
        float s = bqkv[i];
        for (int d = 0; d < CD; d += 4) {
            float4 wv = *(const float4*)(w + d);
            s += wv.x * bq[d] + wv.y * bq[d + 1] + wv.z * bq[d + 2] + wv.w * bq[d + 3];
        }
        beff[i] = s;
    }
}

// beff1[j] = bs1[j] + sum_k Ws1[j][1024+k]*bo[k]
__global__ __launch_bounds__(256) void beff1_kernel(
    const float* __restrict__ Ws1, const float* __restrict__ bo,
    const float* __restrict__ bs1, float* __restrict__ beff1) {
    int j = blockIdx.x * 256 + threadIdx.x;
    if (j < 2 * CD) {
        const float* w = Ws1 + (size_t)j * (2 * CD) + CD;
        float s = bs1[j];
        for (int k = 0; k < CD; k += 4) {
            float4 wv = *(const float4*)(w + k);
            s += wv.x * bo[k] + wv.y * bo[k + 1] + wv.z * bo[k + 2] + wv.w * bo[k + 3];
        }
        beff1[j] = s;
    }
}

// vT[b][h][d][s] = vbuf[b][s][h*128+d]; LDS-tiled 64x64 transpose
__global__ __launch_bounds__(256) void transpose_v_kernel(
    const unsigned short* __restrict__ vbuf, unsigned short* __restrict__ vT) {
    __shared__ unsigned short tile[64][65];
    int bid = blockIdx.x;
    int bh = bid >> 4;
    int tl = bid & 15;
    int s0 = (tl >> 1) * 64, d0 = (tl & 1) * 64;
    int b = bh >> 3, h = bh & 7;
    int sl = threadIdx.x >> 6, dl = threadIdx.x & 63;
#pragma unroll
    for (int it = 0; it < 16; it++) {
        int s = s0 + it * 4 + sl;
        tile[it * 4 + sl][dl] = vbuf[((size_t)(b * CS + s)) * CD + h * CDH + d0 + dl];
    }
    __syncthreads();
    int s2 = threadIdx.x & 63, dr = threadIdx.x >> 6;
#pragma unroll
    for (int it = 0; it < 16; it++) {
        int d = it * 4 + dr;
        vT[((size_t)(bh * CDH + d0 + d)) * CS + s0 + s2] = tile[s2][d];
    }
}

// ---------------------------------------------------------------------------
// Generic MFMA GEMM (reg-staged, XOR swizzle) — used only where A is fp32.
// ---------------------------------------------------------------------------
template <typename TA, typename TW>
__global__ __launch_bounds__(256) void gemm_mfma(
    const TA* __restrict__ A, const TW* __restrict__ W,
    const float* __restrict__ bias, unsigned short* __restrict__ C,
    int N, int K) {
    __shared__ __align__(16) char smem[32768];
    char* As = smem;
    char* Bs = smem + 16384;
    const int tid = threadIdx.x;
    const int row0 = blockIdx.x << 7;
    const int col0 = blockIdx.y << 7;
    const int lane = tid & 63;
    const int wid = tid >> 6;
    const int wr = wid >> 1, wc = wid & 1;
    const int srow_l = tid >> 3;
    const int schunk = tid & 7;

    ffrag acc[4][4];
#pragma unroll
    for (int m = 0; m < 4; m++)
#pragma unroll
        for (int n = 0; n < 4; n++) acc[m][n] = (ffrag)0.0f;

    for (int k0 = 0; k0 < K; k0 += 64) {
        bfrag va[4], vb[4];
#pragma unroll
        for (int i = 0; i < 4; i++) {
            int r = i * 32 + srow_l;
            va[i] = ld8bf(A + (size_t)(row0 + r) * K + k0 + schunk * 8);
            vb[i] = ld8bf(W + (size_t)(col0 + r) * K + k0 + schunk * 8);
        }
#pragma unroll
        for (int i = 0; i < 4; i++) {
            int r = i * 32 + srow_l;
            int pc = schunk ^ (r & 7);
            *(bfrag*)(As + r * 128 + pc * 16) = va[i];
            *(bfrag*)(Bs + r * 128 + pc * 16) = vb[i];
        }
        __syncthreads();
#pragma unroll
        for (int s = 0; s < 2; s++) {
            bfrag af[4], bf[4];
#pragma unroll
            for (int m = 0; m < 4; m++) {
                int r = wr * 64 + m * 16 + (lane & 15);
                int chunk = (s * 4 + (lane >> 4)) ^ (r & 7);
                af[m] = *(const bfrag*)(As + r * 128 + chunk * 16);
            }
#pragma unroll
            for (int n = 0; n < 4; n++) {
                int r = wc * 64 + n * 16 + (lane & 15);
                int chunk = (s * 4 + (lane >> 4)) ^ (r & 7);
                bf[n] = *(const bfrag*)(Bs + r * 128 + chunk * 16);
            }
#pragma unroll
            for (int m = 0; m < 4; m++)
#pragma unroll
                for (int n = 0; n < 4; n++)
                    acc[m][n] = __builtin_amdgcn_mfma_f32_16x16x32_bf16(
                        af[m], bf[n], acc[m][n], 0, 0, 0);
        }
        __syncthreads();
    }

#pragma unroll
    for (int n = 0; n < 4; n++) {
        int col = col0 + wc * 64 + n * 16 + (lane & 15);
        float bv = bias[col];
#pragma unroll
        for (int m = 0; m < 4; m++) {
            int rbase = row0 + wr * 64 + m * 16 + ((lane >> 4) << 2);
#pragma unroll
            for (int j = 0; j < 4; j++) {
                C[(size_t)(rbase + j) * N + col] = f2us(acc[m][n][j] + bv);
            }
        }
    }
}

// ---------------------------------------------------------------------------
// Async MFMA GEMM (bf16 x bf16): global_load_lds width=16 staging, LINEAR
// row-major LDS [128 rows x 128 B] (gload_lds writes base + lane*16 — no
// swizzle possible, rule #21; ds_read bank conflicts accepted per m97/m98).
// ---------------------------------------------------------------------------
__global__ __launch_bounds__(256) void gemm_mfma_async(
    const unsigned short* __restrict__ A, const unsigned short* __restrict__ W,
    const float* __restrict__ bias, unsigned short* __restrict__ C,
    int N, int K) {
    __shared__ __align__(16) char smem[32768];
    char* As = smem;
    char* Bs = smem + 16384;
    const int tid = threadIdx.x;
    const int row0 = blockIdx.x << 7;
    const int col0 = blockIdx.y << 7;
    const int lane = tid & 63;
    const int w = tid >> 6;
    const int wr = w >> 1, wc = w & 1;
    const int lrow = lane >> 3;    // 0..7 within the wave's 8-row group
    const int lchunk = lane & 7;   // 16B chunk within row

    ffrag acc[4][4];
#pragma unroll
    for (int m = 0; m < 4; m++)
#pragma unroll
        for (int n = 0; n < 4; n++) acc[m][n] = (ffrag)0.0f;

    for (int k0 = 0; k0 < K; k0 += 64) {
        // stage A,B: per wave-issue, 64 lanes x 16B = 8 rows x 128B, linear.
#pragma unroll
        for (int i = 0; i < 4; i++) {
            int rbase = i * 32 + w * 8;
            gload_lds16(A + (size_t)(row0 + rbase + lrow) * K + k0 + lchunk * 8,
                        As + rbase * 128);
            gload_lds16(W + (size_t)(col0 + rbase + lrow) * K + k0 + lchunk * 8,
                        Bs + rbase * 128);
        }
        __syncthreads();   // compiler drains vmcnt before barrier
#pragma unroll
        for (int s = 0; s < 2; s++) {
            bfrag af[4], bf[4];
            int ch = s * 4 + (lane >> 4);
#pragma unroll
            for (int m = 0; m < 4; m++) {
                int r = wr * 64 + m * 16 + (lane & 15);
                af[m] = *(const bfrag*)(As + r * 128 + ch * 16);
            }
#pragma unroll
            for (int n = 0; n < 4; n++) {
                int r = wc * 64 + n * 16 + (lane & 15);
                bf[n] = *(const bfrag*)(Bs + r * 128 + ch * 16);
            }
#pragma unroll
            for (int m = 0; m < 4; m++)
#pragma unroll
                for (int n = 0; n < 4; n++)
                    acc[m][n] = __builtin_amdgcn_mfma_f32_16x16x32_bf16(
                        af[m], bf[n], acc[m][n], 0, 0, 0);
        }
        __syncthreads();
    }

#pragma unroll
    for (int n = 0; n < 4; n++) {
        int col = col0 + wc * 64 + n * 16 + (lane & 15);
        float bv = bias[col];
#pragma unroll
        for (int m = 0; m < 4; m++) {
            int rbase = row0 + wr * 64 + m * 16 + ((lane >> 4) << 2);
#pragma unroll
            for (int j = 0; j < 4; j++) {
                C[(size_t)(rbase + j) * N + col] = f2us(acc[m][n][j] + bv);
            }
        }
    }
}

// ---------------------------------------------------------------------------
// Skinny K-split MFMA GEMM body (device fn): P[kz][64][N] partial tile.
// ---------------------------------------------------------------------------
__device__ __forceinline__ void gemm64k_body(
    const unsigned short* __restrict__ A, const unsigned short* __restrict__ W,
    float* __restrict__ P, int N, int K, int kc, int colTile, int kz,
    char* smem) {
    char* As = smem;
    char* Bs = smem + 8192;
    const int tid = threadIdx.x;
    const int col0 = colTile << 6;
    const int kbeg = kz * kc;
    const int lane = tid & 63;
    const int wv = tid >> 6;
    const int srow = tid >> 3;     // 0..31
    const int schunk = tid & 7;

    ffrag acc[4];
#pragma unroll
    for (int n = 0; n < 4; n++) acc[n] = (ffrag)0.0f;

    for (int k0 = kbeg; k0 < kbeg + kc; k0 += 64) {
        bfrag va[2], vb[2];
#pragma unroll
        for (int i = 0; i < 2; i++) {
            int r = i * 32 + srow;
            va[i] = *(const bfrag*)(A + (size_t)r * K + k0 + schunk * 8);
            vb[i] = *(const bfrag*)(W + (size_t)(col0 + r) * K + k0 + schunk * 8);
        }
#pragma unroll
        for (int i = 0; i < 2; i++) {
            int r = i * 32 + srow;
            int pc = schunk ^ (r & 7);
            *(bfrag*)(As + r * 128 + pc * 16) = va[i];
            *(bfrag*)(Bs + r * 128 + pc * 16) = vb[i];
        }
        __syncthreads();
#pragma unroll
        for (int s = 0; s < 2; s++) {
            int r = wv * 16 + (lane & 15);
            int ch = (s * 4 + (lane >> 4)) ^ (r & 7);
            bfrag af = *(const bfrag*)(As + r * 128 + ch * 16);
#pragma unroll
            for (int n = 0; n < 4; n++) {
                int r2 = n * 16 + (lane & 15);
                int ch2 = (s * 4 + (lane >> 4)) ^ (r2 & 7);
                bfrag bf = *(const bfrag*)(Bs + r2 * 128 + ch2 * 16);
                acc[n] = __builtin_amdgcn_mfma_f32_16x16x32_bf16(af, bf, acc[n], 0, 0, 0);
            }
        }
        __syncthreads();
    }

    float* Pz = P + (size_t)kz * 64 * N;
#pragma unroll
    for (int n = 0; n < 4; n++) {
        int col = col0 + n * 16 + (lane & 15);
        int rbase = wv * 16 + ((lane >> 4) << 2);
#pragma unroll
        for (int j = 0; j < 4; j++) {
            Pz[(size_t)(rbase + j) * N + col] = acc[n][j];
        }
    }
}

// standalone gemm64k (used for the attn@Weff2 and ws2 GEMMs)
__global__ __launch_bounds__(256) void gemm64k(
    const unsigned short* __restrict__ A, const unsigned short* __restrict__ W,
    float* __restrict__ P, int N, int K, int kc) {
    __shared__ __align__(16) char smem[16384];
    gemm64k_body(A, W, P, N, K, kc, blockIdx.x, blockIdx.y, smem);
}

// logits body (device fn): one 256-thread group per b.
__device__ __forceinline__ void logits_body(
    int b, const float* __restrict__ s_out, const unsigned short* __restrict__ Wh1b,
    const float* __restrict__ bh1, const float* __restrict__ Wh2,
    const float* __restrict__ bh2, float* __restrict__ out, int t, char* smem) {
    float* so = (float*)smem;        // 512
    float* hh = so + 512;            // 512
    float* red = hh + 512;           // 4
    const int tid = threadIdx.x;
    ((float2*)so)[tid] = ((const float2*)(s_out + (size_t)b * CDO))[tid];
    __syncthreads();
#pragma unroll
    for (int p = 0; p < 2; p++) {
        int j = tid + p * 256;
        const unsigned short* w = Wh1b + (size_t)j * CDO;
        float s = bh1[j];
#pragma unroll 4
        for (int k2 = 0; k2 < CDO; k2 += 4) {
            float4 wv = ld4(w + k2);
            s += wv.x * so[k2] + wv.y * so[k2 + 1] + wv.z * so[k2 + 2] + wv.w * so[k2 + 3];
        }
        hh[j] = gelu_exact(s);
    }
    __syncthreads();
    float part = hh[tid] * Wh2[tid] + hh[tid + 256] * Wh2[tid + 256];
#pragma unroll
    for (int off = 32; off; off >>= 1) part += __shfl_down(part, off, 64);
    if ((tid & 63) == 0) red[tid >> 6] = part;
    __syncthreads();
    if (tid == 0) out[b * CT + t] = red[0] + red[1] + red[2] + red[3] + bh2[0];
}

// ---------------------------------------------------------------------------
// mid_kernel: the three independent consumers of sync's outputs in ONE launch.
// blocks 0..127   : qh partials  (s_act @ Weff^T  -> Pq;  16 col x 8 kz)
// blocks 128..383 : zpart        (zb16 @ Ws1a^T   -> P2;  32 col x 8 kz)
// blocks 384..447 : logits       (64 blocks, one per b)
// ---------------------------------------------------------------------------
__global__ __launch_bounds__(256) void mid_kernel(
    const unsigned short* __restrict__ s_act, const unsigned short* __restrict__ weff,
    float* __restrict__ Pq,
    const unsigned short* __restrict__ zb16, const unsigned short* __restrict__ ws1a,
    float* __restrict__ P2,
    const float* __restrict__ s_out, const unsigned short* __restrict__ wh1_b,
    const float* __restrict__ bh1, const float* __restrict__ Wh2,
    const float* __restrict__ bh2, float* __restrict__ out, int t) {
    __shared__ __align__(16) char smem[16384];
    const int blk = blockIdx.x;
    if (blk < 128) {
        gemm64k_body(s_act, weff, Pq, CD, CDA, CDA / 8, blk & 15, blk >> 4, smem);
    } else if (blk < 384) {
        int idx = blk - 128;
        gemm64k_body(zb16, ws1a, P2, 2 * CD, CD, CD / 8, idx & 31, idx >> 5, smem);
    } else {
        logits_body(blk - 384, s_out, wh1_b, bh1, Wh2, bh2, out, t, smem);
    }
}

// LayerNorm + GELU, in place on bf16 h rows.
__global__ __launch_bounds__(256) void ln_gelu_kernel(
    unsigned short* __restrict__ hc, const float* __restrict__ g,
    const float* __restrict__ bb) {
    __shared__ float sred[4];
    const int tid = threadIdx.x;
    size_t base = (size_t)blockIdx.x * CD;
    float4 x = ld4(hc + base + tid * 4);
    float s = x.x + x.y + x.z + x.w;
#pragma unroll
    for (int off = 32; off; off >>= 1) s += __shfl_down(s, off, 64);
    if ((tid & 63) == 0) sred[tid >> 6] = s;
    __syncthreads();
    float mu = (sred[0] + sred[1] + sred[2] + sred[3]) * (1.0f / 1024.0f);
    float d0 = x.x - mu, d1 = x.y - mu, d2 = x.z - mu, d3 = x.w - mu;
    float sq = d0 * d0 + d1 * d1 + d2 * d2 + d3 * d3;
    __syncthreads();
#pragma unroll
    for (int off = 32; off; off >>= 1) sq += __shfl_down(sq, off, 64);
    if ((tid & 63) == 0) sred[tid >> 6] = sq;
    __syncthreads();
    float var = (sred[0] + sred[1] + sred[2] + sred[3]) * (1.0f / 1024.0f);
    float rs = 1.0f / sqrtf(var + 1e-5f);
    float4 gv = ((const float4*)g)[tid];
    float4 bv = ((const float4*)bb)[tid];
    float4 o;
    o.x = gelu_exact(d0 * rs * gv.x + bv.x);
    o.y = gelu_exact(d1 * rs * gv.y + bv.y);
    o.z = gelu_exact(d2 * rs * gv.z + bv.z);
    o.w = gelu_exact(d3 * rs * gv.w + bv.w);
    st4(hc + base + tid * 4, o);
}

// zbufT[b][d][ts]: ts=0 -> z_init[d], else 0; hist = broadcast hist_init.
__global__ __launch_bounds__(256) void init_kernel(
    const float* __restrict__ z_init, const float* __restrict__ hist_init,
    float* __restrict__ zbufT, float* __restrict__ hist) {
    int i = blockIdx.x * 256 + threadIdx.x;
    if (i < CB * CD * CTP1) {
        int rem = i % (CD * CTP1);
        int d = rem / CTP1;
        int ts = rem - d * CTP1;
        zbufT[i] = (ts == 0) ? z_init[d] : 0.0f;
    }
    if (i < CB * CD * CM) {
        hist[i] = hist_init[i % (CD * CM)];
    }
}

// sync: s_act(bf16), s_out(fp32), zb16(bf16 z snapshot) for step t.
__global__ __launch_bounds__(256) void sync_kernel(
    const float* __restrict__ zbufT,
    const float* __restrict__ decay_a, const float* __restrict__ decay_o,
    const int* __restrict__ iia, const int* __restrict__ jja,
    const int* __restrict__ iio, const int* __restrict__ jjo,
    unsigned short* __restrict__ s_act, float* __restrict__ s_out,
    unsigned short* __restrict__ zb16, int t) {
    int b = blockIdx.x >> 2;
    int sg = ((blockIdx.x & 3) << 8) + threadIdx.x;  // 0..1023
    const float* zbT = zbufT + (size_t)b * CD * CTP1;
    zb16[b * CD + sg] = f2us(zbT[(size_t)sg * CTP1 + t]);
    float soft;
    int ii, jj;
    if (sg < CDA) {
        soft = softplusf(decay_a[sg]);
        ii = iia[sg]; jj = jja[sg];
    } else {
        int s2 = sg - CDA;
        soft = softplusf(decay_o[s2]);
        ii = iio[s2]; jj = jjo[s2];
    }
    const float* zi = zbT + (size_t)ii * CTP1;
    const float* zj = zbT + (size_t)jj * CTP1;
    float num = 0.0f, den = 0.0f;
    for (int ts = 0; ts <= t; ts++) {
        float w = expf(-soft * (float)(t - ts));
        num += zi[ts] * zj[ts] * w;
        den += w * w;
    }
    float val = num / sqrtf(den + 1e-8f);
    if (sg < CDA) s_act[b * CDA + sg] = f2us(val);
    else s_out[b * CDO + (sg - CDA)] = val;
}

// ---------------------------------------------------------------------------
// Attention, one (b,h) pair per 512-thread block. r8-verified coalesced
// double-buffered LDS streaming; qh assembled from K-split partials (Pq+beff).
// smem carve (43648 B): buf0 [0,18432) buf1 [18432,36864) att [36864,38912)
// qv [38912,39424) pacc [39424,41472) ppv [41472,43520) red [43520,43584)
// ---------------------------------------------------------------------------
__global__ __launch_bounds__(512) void attn512_kernel(
    const float* __restrict__ Pq, const float* __restrict__ beff,
    const unsigned short* __restrict__ kb, const unsigned short* __restrict__ vT,
    unsigned short* __restrict__ attn_out) {
    __shared__ __align__(16) char smraw[43648];
    char* buf0 = smraw;
    char* buf1 = smraw + 18432;
    float* att  = (float*)(smraw + 36864);
    float* qv   = (float*)(smraw + 38912);
    float* pacc = (float*)(smraw + 39424);
    float* ppv  = (float*)(smraw + 41472);
    float* red  = (float*)(smraw + 43520);
    const int tid = threadIdx.x;
    const int lane = tid & 63;
    const int wv = tid >> 6;
    const int pair = blockIdx.x;
    const int b = pair >> 3, h = pair & 7;
    const float scale = 0.08838834764831845f;  // 1/sqrt(128)

    if (tid < CDH) {
        int col = h * CDH + tid;
        float q = beff[col];
#pragma unroll
        for (int z = 0; z < 8; z++) q += Pq[((size_t)(z * 64 + b)) * CD + col];
        qv[tid] = q;
    }

    // ---- QK^T over 8 chunks of [64 s][128 d] (rows padded to 272 B) ----
    const unsigned short* kbase = kb + (size_t)(b * CS) * CD + h * CDH;
    const int sR0 = tid >> 4, c16 = tid & 15;   // stage: 16 thr/row
    {
        bfrag a = *(const bfrag*)(kbase + (size_t)sR0 * CD + c16 * 8);
        bfrag bb = *(const bfrag*)(kbase + (size_t)(sR0 + 32) * CD + c16 * 8);
        *(bfrag*)(buf0 + sR0 * 272 + c16 * 16) = a;
        *(bfrag*)(buf0 + (sR0 + 32) * 272 + c16 * 16) = bb;
    }
    __syncthreads();
    const int sC = tid & 63, g = wv;            // compute: thread (s, d-group)
    for (int c = 0; c < 8; c++) {
        char* cur = (c & 1) ? buf1 : buf0;
        char* nxt = (c & 1) ? buf0 : buf1;
        bfrag pa, pb;
        if (c < 7) {
            pa = *(const bfrag*)(kbase + (size_t)((c + 1) * 64 + sR0) * CD + c16 * 8);
            pb = *(const bfrag*)(kbase + (size_t)((c + 1) * 64 + sR0 + 32) * CD + c16 * 8);
        }
        {
            bfrag k0 = *(const bfrag*)(cur + sC * 272 + g * 32);
            bfrag k1 = *(const bfrag*)(cur + sC * 272 + g * 32 + 16);
            float s = 0.0f;
#pragma unroll
            for (int e = 0; e < 8; e++) {
                s += us2f((unsigned short)k0[e]) * qv[g * 16 + e];
                s += us2f((unsigned short)k1[e]) * qv[g * 16 + 8 + e];
            }
            pacc[g * 64 + sC] = s;
        }
        __syncthreads();
        if (c < 7) {
            *(bfrag*)(nxt + sR0 * 272 + c16 * 16) = pa;
            *(bfrag*)(nxt + (sR0 + 32) * 272 + c16 * 16) = pb;
        }
        if (tid < 64) {
            float s = 0.0f;
#pragma unroll
            for (int gg = 0; gg < 8; gg++) s += pacc[gg * 64 + tid];
            att[c * 64 + tid] = s * scale;
        }
        __syncthreads();
    }

    // ---- prefetch v chunk 0 while softmax runs ----
    const unsigned short* vbase = vT + (size_t)((b * CNH + h) * CDH) * CS;
    const int dR0 = tid >> 3, c8 = tid & 7;     // stage: 8 thr/row
    bfrag v0a = *(const bfrag*)(vbase + (size_t)dR0 * CS + c8 * 8);
    bfrag v0b = *(const bfrag*)(vbase + (size_t)(dR0 + 64) * CS + c8 * 8);

    // ---- softmax over att[512] (one value per thread) ----
    {
        float v = att[tid];
        float m = v;
#pragma unroll
        for (int o = 32; o; o >>= 1) m = fmaxf(m, __shfl_down(m, o, 64));
        if (lane == 0) red[wv] = m;
        __syncthreads();
        float mx = red[0];
#pragma unroll
        for (int r = 1; r < 8; r++) mx = fmaxf(mx, red[r]);
        float e = expf(v - mx);
        float s = e;
#pragma unroll
        for (int o = 32; o; o >>= 1) s += __shfl_down(s, o, 64);
        __syncthreads();
        if (lane == 0) red[8 + wv] = s;
        __syncthreads();
        float tot = 0.0f;
#pragma unroll
        for (int r = 0; r < 8; r++) tot += red[8 + r];
        att[tid] = e / tot;   // normalized probability
    }
    // write v chunk 0 (buf0 free: last QK compute used buf1)
    *(bfrag*)(buf0 + dR0 * 144 + c8 * 16) = v0a;
    *(bfrag*)(buf0 + (dR0 + 64) * 144 + c8 * 16) = v0b;
    __syncthreads();

    // ---- PV over 8 chunks of [128 d][64 s] (rows padded to 144 B) ----
    const int dC = tid & 127, q = tid >> 7;     // compute: thread (d, s-group)
    float pv = 0.0f;
    for (int c = 0; c < 8; c++) {
        char* cur = (c & 1) ? buf1 : buf0;
        char* nxt = (c & 1) ? buf0 : buf1;
        bfrag pa, pb;
        if (c < 7) {
            pa = *(const bfrag*)(vbase + (size_t)dR0 * CS + (c + 1) * 64 + c8 * 8);
            pb = *(const bfrag*)(vbase + (size_t)(dR0 + 64) * CS + (c + 1) * 64 + c8 * 8);
        }
        {
            bfrag w0 = *(const bfrag*)(cur + dC * 144 + q * 32);
            bfrag w1 = *(const bfrag*)(cur + dC * 144 + q * 32 + 16);
            const float* ap = att + c * 64 + q * 16;
#pragma unroll
            for (int e = 0; e < 8; e++) {
                pv += us2f((unsigned short)w0[e]) * ap[e];
                pv += us2f((unsigned short)w1[e]) * ap[8 + e];
            }
        }
        __syncthreads();
        if (c < 7) {
            *(bfrag*)(nxt + dR0 * 144 + c8 * 16) = pa;
            *(bfrag*)(nxt + (dR0 + 64) * 144 + c8 * 16) = pb;
        }
        __syncthreads();
    }
    ppv[q * 128 + dC] = pv;
    __syncthreads();
    if (tid < CDH) {
        float o = ppv[tid] + ppv[128 + tid] + ppv[256 + tid] + ppv[384 + tid];
        attn_out[(size_t)b * CD + h * CDH + tid] = f2us(o);
    }
}

// pre1 = gelu(sum_z P2 + sum_z P3 + beff1); i over 64x2048.
__global__ __launch_bounds__(256) void pre1r_kernel(
    const float* __restrict__ P2, const float* __restrict__ P3,
    const float* __restrict__ beff1, unsigned short* __restrict__ pre1) {
    int i = blockIdx.x * 256 + threadIdx.x;
    int j = i & 2047;
    float v = beff1[j];
#pragma unroll
    for (int z = 0; z < 8; z++)
        v += P2[(size_t)z * 131072 + i] + P3[(size_t)z * 131072 + i];
    pre1[i] = f2us(gelu_exact(v));
}

// pre = sum_z Pw + bs2, fused neuron MLP -> zbufT[:,:,t+1]; idx over (b,d).
__global__ __launch_bounds__(256) void ws2r_neuron_kernel(
    const float* __restrict__ Pw, const float* __restrict__ bs2,
    float* __restrict__ hist,
    const float* __restrict__ Wn1, const float* __restrict__ bn1,
    const float* __restrict__ Wn2, const float* __restrict__ bn2,
    const float* __restrict__ Wn3, const float* __restrict__ bn3,
    float* __restrict__ zbufT, int t) {
    int idx = blockIdx.x * 256 + threadIdx.x;  // (b,d)
    int d = idx & 1023;
    float prev = bs2[d];
#pragma unroll
    for (int z = 0; z < 8; z++) prev += Pw[(size_t)z * 65536 + idx];
    float hv[CM];
    float* hp = hist + (size_t)idx * CM;
#pragma unroll
    for (int m = 0; m < CM - 1; m++) hv[m] = hp[m + 1];
    hv[CM - 1] = prev;
#pragma unroll
    for (int m = 0; m < CM; m++) hp[m] = hv[m];
    float x1[CH];
#pragma unroll
    for (int hh = 0; hh < CH; hh++) {
        const float* w = Wn1 + ((size_t)d * CH + hh) * CM;
        float s = bn1[d * CH + hh];
#pragma unroll
        for (int m = 0; m < CM; m++) s += hv[m] * w[m];
        x1[hh] = gelu_exact(s);
    }
    float x2[CH];
#pragma unroll
    for (int g = 0; g < CH; g++) {
        float s = bn2[d * CH + g];
#pragma unroll
        for (int hh = 0; hh < CH; hh++) s += x1[hh] * Wn2[((size_t)d * CH + g) * CH + hh];
        x2[g] = gelu_exact(s);
    }
    float z = bn3[d];
#pragma unroll
    for (int hh = 0; hh < CH; hh++) z += x2[hh] * Wn3[d * CH + hh];
    zbufT[(size_t)idx * CTP1 + (t + 1)] = z;
}

// Writes v to all outputs; v encodes ws_size in MB so a failure is decodable.
__global__ void sentinel_kernel(float* out, float v) {
    int i = blockIdx.x * 256 + threadIdx.x;
    if (i < CB * CT) out[i] = v;
}

extern "C" void kernel_launch(void* const* d_in, const int* in_sizes, int n_in,
                              void* d_out, int out_size, void* d_ws, size_t ws_size,
                              hipStream_t stream) {
    const float* emb = (const float*)d_in[0];
    const float* Wp = (const float*)d_in[1];
    const float* bp = (const float*)d_in[2];
    const float* ln_g = (const float*)d_in[3];
    const float* ln_b = (const float*)d_in[4];
    const float* decay_a = (const float*)d_in[5];
    const float* decay_o = (const float*)d_in[6];
    const float* Wq = (const float*)d_in[7];
    const float* bq = (const float*)d_in[8];
    const float* Wqkv = (const float*)d_in[9];
    const float* bqkv = (const float*)d_in[10];
    const float* Wo = (const float*)d_in[11];
    const float* bo = (const float*)d_in[12];
    const float* Ws1 = (const float*)d_in[13];
    const float* bs1 = (const float*)d_in[14];
    const float* Ws2 = (const float*)d_in[15];
    const float* bs2 = (const float*)d_in[16];
    const float* Wn1 = (const float*)d_in[17];
    const float* bn1 = (const float*)d_in[18];
    const float* Wn2 = (const float*)d_in[19];
    const float* bn2 = (const float*)d_in[20];
    const float* Wn3 = (const float*)d_in[21];
    const float* bn3 = (const float*)d_in[22];
    const float* Wh1 = (const float*)d_in[23];
    const float* bh1 = (const float*)d_in[24];
    const float* Wh2 = (const float*)d_in[25];
    const float* bh2 = (const float*)d_in[26];
    const float* z_init = (const float*)d_in[27];
    const float* hist_init = (const float*)d_in[28];
    const int* iia = (const int*)d_in[29];
    const int* jja = (const int*)d_in[30];
    const int* iio = (const int*)d_in[31];
    const int* jjo = (const int*)d_in[32];
    float* out = (float*)d_out;

    char* wsb = (char*)d_ws;
    size_t off = 0;
    auto alloc = [&](size_t bytes) {
        void* p = wsb + off;
        off += (bytes + 255) & ~(size_t)255;
        return p;
    };
    unsigned short* ctx  = (unsigned short*)alloc((size_t)CB * CS * CD * 2);  // h/ctx, later vT
    unsigned short* kbuf = (unsigned short*)alloc((size_t)CB * CS * CD * 2);
    unsigned short* vbuf = (unsigned short*)alloc((size_t)CB * CS * CD * 2);
    float* zbufT = (float*)alloc((size_t)CB * CD * CTP1 * 4);
    float* hist = (float*)alloc((size_t)CB * CD * CM * 4);
    unsigned short* s_act = (unsigned short*)alloc((size_t)CB * CDA * 2);
    float* s_out = (float*)alloc((size_t)CB * CDO * 4);
    unsigned short* zb16 = (unsigned short*)alloc((size_t)CB * CD * 2);
    unsigned short* attn_out = (unsigned short*)alloc((size_t)CB * CD * 2);
    unsigned short* pre1 = (unsigned short*)alloc((size_t)CB * 2 * CD * 2);
    // K-split partial buffers (fp32). Pq doubles as Pw (disjoint lifetimes).
    float* Pq = (float*)alloc((size_t)8 * 64 * CD * 4);          // 2 MB
    float* P2 = (float*)alloc((size_t)8 * 64 * 2 * CD * 4);      // 4 MB
    float* P3 = (float*)alloc((size_t)8 * 64 * 2 * CD * 4);      // 4 MB
    // bf16 weights / fused weights
    unsigned short* wqkv_b = (unsigned short*)alloc((size_t)3 * CD * CD * 2);
    unsigned short* ws2_b = (unsigned short*)alloc((size_t)CD * 2 * CD * 2);
    unsigned short* wh1_b = (unsigned short*)alloc((size_t)CDO * CDO * 2);
    unsigned short* wqT_b = (unsigned short*)alloc((size_t)CDA * CD * 2);
    unsigned short* weff_b = (unsigned short*)alloc((size_t)CD * CDA * 2);
    unsigned short* ws1a_b = (unsigned short*)alloc((size_t)2 * CD * CD * 2);
    unsigned short* ws1b_b = (unsigned short*)alloc((size_t)2 * CD * CD * 2);
    unsigned short* woT_b = (unsigned short*)alloc((size_t)CD * CD * 2);
    unsigned short* weff2_b = (unsigned short*)alloc((size_t)2 * CD * CD * 2);
    float* beff = (float*)alloc((size_t)CD * 4);
    float* beff1 = (float*)alloc((size_t)2 * CD * 4);
    float* zbias = (float*)alloc((size_t)2 * CD * 4);
    unsigned short* vT = ctx;  // alias: ctx dead after the v GEMM

    if (off > ws_size) {
        sentinel_kernel<<<dim3(4), dim3(256), 0, stream>>>(out, -(float)(ws_size >> 20));
        return;
    }

    // ---- One-time setup ----
    auto conv = [&](const float* s, unsigned short* d, size_t n) {
        int n4 = (int)(n / 4);
        convert_bf16_kernel<<<dim3((n4 + 255) / 256), 256, 0, stream>>>(s, d, n4);
    };
    conv(Wqkv, wqkv_b, (size_t)3 * CD * CD);
    conv(Ws2, ws2_b, (size_t)CD * 2 * CD);
    conv(Wh1, wh1_b, (size_t)CDO * CDO);
    transpose_wq_kernel<<<dim3((CDA * CD + 255) / 256), 256, 0, stream>>>(Wq, wqT_b);
    transpose_wo_kernel<<<dim3((CD * CD + 255) / 256), 256, 0, stream>>>(Wo, woT_b);
    pack_ws1_kernel<<<dim3((2 * CD * CD + 255) / 256), 256, 0, stream>>>(Ws1, ws1a_b, ws1b_b);
    hipMemsetAsync(zbias, 0, (size_t)2 * CD * 4, stream);
    beff_kernel<<<dim3(4), 256, 0, stream>>>(Wqkv, bq, bqkv, beff);
    beff1_kernel<<<dim3(8), 256, 0, stream>>>(Ws1, bo, bs1, beff1);
    // Weff = Wq3 @ Wq  (1024 x 512, K=1024)
    gemm_mfma_async<<<dim3(CD / 128, CDA / 128), 256, 0, stream>>>(
        wqkv_b, wqT_b, zbias, weff_b, CDA, CD);
    // Weff2 = Ws1b @ Wo  (2048 x 1024, K=1024)
    gemm_mfma_async<<<dim3(2 * CD / 128, CD / 128), 256, 0, stream>>>(
        ws1b_b, woT_b, zbias, weff2_b, CD, CD);

    // ---- Phase A ----
    gemm_mfma<float, float><<<dim3(CB * CS / 128, CD / 128), 256, 0, stream>>>(
        emb, Wp, bp, ctx, CD, CDE);
    ln_gelu_kernel<<<dim3(CB * CS), 256, 0, stream>>>(ctx, ln_g, ln_b);
    gemm_mfma_async<<<dim3(CB * CS / 128, CD / 128), 256, 0, stream>>>(
        ctx, wqkv_b + (size_t)CD * CD, bqkv + CD, kbuf, CD, CD);
    gemm_mfma_async<<<dim3(CB * CS / 128, CD / 128), 256, 0, stream>>>(
        ctx, wqkv_b + (size_t)2 * CD * CD, bqkv + 2 * CD, vbuf, CD, CD);
    // vT[b][h][d][s] (aliases ctx — ctx is dead now)
    transpose_v_kernel<<<dim3(CB * CNH * 16), 256, 0, stream>>>(vbuf, vT);
    init_kernel<<<dim3(4352), 256, 0, stream>>>(z_init, hist_init, zbufT, hist);

    // ---- Phase B: 16 steps, 6 launches each ----
    for (int t = 0; t < CT; t++) {
        sync_kernel<<<dim3(256), 256, 0, stream>>>(
            zbufT, decay_a, decay_o, iia, jja, iio, jjo, s_act, s_out, zb16, t);
        // qh partials + zpart partials + logits in ONE launch
        mid_kernel<<<dim3(448), 256, 0, stream>>>(
            s_act, weff_b, Pq, zb16, ws1a_b, P2, s_out, wh1_b, bh1, Wh2, bh2, out, t);
        // attention (sums Pq internally)
        attn512_kernel<<<dim3(CB * CNH), 512, 0, stream>>>(Pq, beff, kbuf, vT, attn_out);
        // attn @ Weff2^T partials (N=2048, K=1024)
        gemm64k<<<dim3(32, 8), 256, 0, stream>>>(attn_out, weff2_b, P3, 2 * CD, CD, CD / 8);
        // pre1 = gelu(zpart + attnpart + beff1)
        pre1r_kernel<<<dim3(512), 256, 0, stream>>>(P2, P3, beff1, pre1);
        // ws2 partials: pre1 @ Ws2^T (N=1024, K=2048); Pw aliases Pq
        gemm64k<<<dim3(16, 8), 256, 0, stream>>>(pre1, ws2_b, Pq, CD, 2 * CD, 2 * CD / 8);
        // pre reduce + neuron MLP -> zbufT[:,:,t+1]
        ws2r_neuron_kernel<<<dim3(256), 256, 0, stream>>>(
            Pq, bs2, hist, Wn1, bn1, Wn2, bn2, Wn3, bn3, zbufT, t);
    }
}

// Round 15
// 1582.825 us; speedup vs baseline: 1.0073x; 1.0073x over previous
//
#include <hip/hip_runtime.h>
#include <hip/hip_bf16.h>

constexpr int CB = 64;     // batch
constexpr int CS = 512;    // seq
constexpr int CDE = 384;   // embed dim
constexpr int CD = 1024;   // model dim
constexpr int CM = 16;     // hist depth
constexpr int CH = 4;      // neuron hidden
constexpr int CNH = 8;     // heads
constexpr int CDH = 128;   // head dim
constexpr int CDA = 512;
constexpr int CDO = 512;
constexpr int CT = 16;     // T_MAX
constexpr int CTP1 = 17;

typedef __attribute__((ext_vector_type(8))) short bfrag;   // 8 bf16 (4 VGPRs)
typedef __attribute__((ext_vector_type(4))) float ffrag;   // MFMA accumulator

__device__ __forceinline__ float gelu_exact(float x) {
    return 0.5f * x * (1.0f + erff(x * 0.70710678118654752440f));
}
__device__ __forceinline__ float softplusf(float x) {
    return fmaxf(x, 0.0f) + log1pf(expf(-fabsf(x)));
}
__device__ __forceinline__ float us2f(unsigned short u) {
    union { unsigned int i; float f; } c; c.i = ((unsigned int)u) << 16; return c.f;
}
__device__ __forceinline__ unsigned short f2us(float x) {
    __hip_bfloat16 b = __float2bfloat16(x);  // RNE
    union { __hip_bfloat16 b; unsigned short u; } c; c.b = b; return c.u;
}

template <typename T>
__device__ __forceinline__ float4 ld4(const T* p);
template <>
__device__ __forceinline__ float4 ld4<float>(const float* p) { return *(const float4*)p; }
template <>
__device__ __forceinline__ float4 ld4<unsigned short>(const unsigned short* p) {
    ushort4 u = *(const ushort4*)p;
    return make_float4(us2f(u.x), us2f(u.y), us2f(u.z), us2f(u.w));
}
__device__ __forceinline__ void st4(float* p, float4 v) { *(float4*)p = v; }
__device__ __forceinline__ void st4(unsigned short* p, float4 v) {
    ushort4 u = make_ushort4(f2us(v.x), f2us(v.y), f2us(v.z), f2us(v.w));
    *(ushort4*)p = u;
}

__device__ __forceinline__ bfrag ld8bf(const unsigned short* p) {
    return *(const bfrag*)p;
}
__device__ __forceinline__ bfrag ld8bf(const float* p) {
    float4 a = *(const float4*)p;
    float4 b = *(const float4*)(p + 4);
    bfrag v;
    v[0] = (short)f2us(a.x); v[1] = (short)f2us(a.y);
    v[2] = (short)f2us(a.z); v[3] = (short)f2us(a.w);
    v[4] = (short)f2us(b.x); v[5] = (short)f2us(b.y);
    v[6] = (short)f2us(b.z); v[7] = (short)f2us(b.w);
    return v;
}

// fp32 -> bf16 bulk convert (n divisible by 4)
__global__ __launch_bounds__(256) void convert_bf16_kernel(
    const float* __restrict__ src, unsigned short* __restrict__ dst, int n4) {
    int i = blockIdx.x * 256 + threadIdx.x;
    if (i < n4) {
        float4 v = *(const float4*)(src + (size_t)i * 4);
        st4(dst + (size_t)i * 4, v);
    }
}

// WqT[a][d] = Wq[d][a] (bf16); Wq is [CD][CDA]
__global__ __launch_bounds__(256) void transpose_wq_kernel(
    const float* __restrict__ Wq, unsigned short* __restrict__ WqT) {
    int i = blockIdx.x * 256 + threadIdx.x;
    if (i < CDA * CD) {
        int a = i / CD, d = i - a * CD;
        WqT[i] = f2us(Wq[(size_t)d * CDA + a]);
    }
}

// woT[d][k] = Wo[k][d] (bf16); Wo is [CD][CD]
__global__ __launch_bounds__(256) void transpose_wo_kernel(
    const float* __restrict__ Wo, unsigned short* __restrict__ WoT) {
    int i = blockIdx.x * 256 + threadIdx.x;
    if (i < CD * CD) {
        int d = i >> 10, k = i & 1023;
        WoT[i] = f2us(Wo[(size_t)k * CD + d]);
    }
}

// Split Ws1 into packed bf16 halves ws1a (cols 0..1023), ws1b (1024..2047)
__global__ __launch_bounds__(256) void pack_ws1_kernel(
    const float* __restrict__ Ws1, unsigned short* __restrict__ ws1a,
    unsigned short* __restrict__ ws1b) {
    int i = blockIdx.x * 256 + threadIdx.x;
    if (i < 2 * CD * CD) {
        int j = i >> 10, k = i & 1023;
        ws1a[i] = f2us(Ws1[(size_t)j * (2 * CD) + k]);
        ws1b[i] = f2us(Ws1[(size_t)j * (2 * CD) + CD + k]);
    }
}

// beff[i] = bq3[i] + sum_d Wq3[i,d]*bq[d]
__global__ __launch_bounds__(256) void beff_kernel(
    const float* __restrict__ Wqkv, const float* __restrict__ bq,
    const float* __restrict__ bqkv, float* __restrict__ beff) {
    int i = blockIdx.x * 256 + threadIdx.x;
    if (i < CD) {
        const float* w = Wqkv + (size_t)i * CD;
        float s = bqkv[i];
        for (int d = 0; d < CD; d += 4) {
            float4 wv = *(const float4*)(w + d);
            s += wv.x * bq[d] + wv.y * bq[d + 1] + wv.z * bq[d + 2] + wv.w * bq[d + 3];
        }
        beff[i] = s;
    }
}

// beff1[j] = bs1[j] + sum_k Ws1[j][1024+k]*bo[k]
__global__ __launch_bounds__(256) void beff1_kernel(
    const float* __restrict__ Ws1, const float* __restrict__ bo,
    const float* __restrict__ bs1, float* __restrict__ beff1) {
    int j = blockIdx.x * 256 + threadIdx.x;
    if (j < 2 * CD) {
        const float* w = Ws1 + (size_t)j * (2 * CD) + CD;
        float s = bs1[j];
        for (int k = 0; k < CD; k += 4) {
            float4 wv = *(const float4*)(w + k);
            s += wv.x * bo[k] + wv.y * bo[k + 1] + wv.z * bo[k + 2] + wv.w * bo[k + 3];
        }
        beff1[j] = s;
    }
}

// vT[b][h][d][s] = vbuf[b][s][h*128+d]; LDS-tiled 64x64 transpose
__global__ __launch_bounds__(256) void transpose_v_kernel(
    const unsigned short* __restrict__ vbuf, unsigned short* __restrict__ vT) {
    __shared__ unsigned short tile[64][65];
    int bid = blockIdx.x;
    int bh = bid >> 4;
    int tl = bid & 15;
    int s0 = (tl >> 1) * 64, d0 = (tl & 1) * 64;
    int b = bh >> 3, h = bh & 7;
    int sl = threadIdx.x >> 6, dl = threadIdx.x & 63;
#pragma unroll
    for (int it = 0; it < 16; it++) {
        int s = s0 + it * 4 + sl;
        tile[it * 4 + sl][dl] = vbuf[((size_t)(b * CS + s)) * CD + h * CDH + d0 + dl];
    }
    __syncthreads();
    int s2 = threadIdx.x & 63, dr = threadIdx.x >> 6;
#pragma unroll
    for (int it = 0; it < 16; it++) {
        int d = it * 4 + dr;
        vT[((size_t)(bh * CDH + d0 + d)) * CS + s0 + s2] = tile[s2][d];
    }
}

// ---------------------------------------------------------------------------
// MFMA GEMM: C[M,N](bf16) = A[M,K] @ W[N,K]^T + bias.  128x128 tile.
// Reg-staged, XOR-swizzled LDS (0 bank conflicts, verified r3-r13).
// ---------------------------------------------------------------------------
template <typename TA, typename TW>
__global__ __launch_bounds__(256) void gemm_mfma(
    const TA* __restrict__ A, const TW* __restrict__ W,
    const float* __restrict__ bias, unsigned short* __restrict__ C,
    int N, int K) {
    __shared__ __align__(16) char smem[32768];
    char* As = smem;
    char* Bs = smem + 16384;
    const int tid = threadIdx.x;
    const int row0 = blockIdx.x << 7;
    const int col0 = blockIdx.y << 7;
    const int lane = tid & 63;
    const int wid = tid >> 6;
    const int wr = wid >> 1, wc = wid & 1;
    const int srow_l = tid >> 3;
    const int schunk = tid & 7;

    ffrag acc[4][4];
#pragma unroll
    for (int m = 0; m < 4; m++)
#pragma unroll
        for (int n = 0; n < 4; n++) acc[m][n] = (ffrag)0.0f;

    for (int k0 = 0; k0 < K; k0 += 64) {
        bfrag va[4], vb[4];
#pragma unroll
        for (int i = 0; i < 4; i++) {
            int r = i * 32 + srow_l;
            va[i] = ld8bf(A + (size_t)(row0 + r) * K + k0 + schunk * 8);
            vb[i] = ld8bf(W + (size_t)(col0 + r) * K + k0 + schunk * 8);
        }
#pragma unroll
        for (int i = 0; i < 4; i++) {
            int r = i * 32 + srow_l;
            int pc = schunk ^ (r & 7);
            *(bfrag*)(As + r * 128 + pc * 16) = va[i];
            *(bfrag*)(Bs + r * 128 + pc * 16) = vb[i];
        }
        __syncthreads();
#pragma unroll
        for (int s = 0; s < 2; s++) {
            bfrag af[4], bf[4];
#pragma unroll
            for (int m = 0; m < 4; m++) {
                int r = wr * 64 + m * 16 + (lane & 15);
                int chunk = (s * 4 + (lane >> 4)) ^ (r & 7);
                af[m] = *(const bfrag*)(As + r * 128 + chunk * 16);
            }
#pragma unroll
            for (int n = 0; n < 4; n++) {
                int r = wc * 64 + n * 16 + (lane & 15);
                int chunk = (s * 4 + (lane >> 4)) ^ (r & 7);
                bf[n] = *(const bfrag*)(Bs + r * 128 + chunk * 16);
            }
#pragma unroll
            for (int m = 0; m < 4; m++)
#pragma unroll
                for (int n = 0; n < 4; n++)
                    acc[m][n] = __builtin_amdgcn_mfma_f32_16x16x32_bf16(
                        af[m], bf[n], acc[m][n], 0, 0, 0);
        }
        __syncthreads();
    }

#pragma unroll
    for (int n = 0; n < 4; n++) {
        int col = col0 + wc * 64 + n * 16 + (lane & 15);
        float bv = bias[col];
#pragma unroll
        for (int m = 0; m < 4; m++) {
            int rbase = row0 + wr * 64 + m * 16 + ((lane >> 4) << 2);
#pragma unroll
            for (int j = 0; j < 4; j++) {
                C[(size_t)(rbase + j) * N + col] = f2us(acc[m][n][j] + bv);
            }
        }
    }
}

// ---------------------------------------------------------------------------
// Skinny K-split MFMA GEMM body (device fn): P[kz][64][N] partial tile.
// ---------------------------------------------------------------------------
__device__ __forceinline__ void gemm64k_body(
    const unsigned short* __restrict__ A, const unsigned short* __restrict__ W,
    float* __restrict__ P, int N, int K, int kc, int colTile, int kz,
    char* smem) {
    char* As = smem;
    char* Bs = smem + 8192;
    const int tid = threadIdx.x;
    const int col0 = colTile << 6;
    const int kbeg = kz * kc;
    const int lane = tid & 63;
    const int wv = tid >> 6;
    const int srow = tid >> 3;     // 0..31
    const int schunk = tid & 7;

    ffrag acc[4];
#pragma unroll
    for (int n = 0; n < 4; n++) acc[n] = (ffrag)0.0f;

    for (int k0 = kbeg; k0 < kbeg + kc; k0 += 64) {
        bfrag va[2], vb[2];
#pragma unroll
        for (int i = 0; i < 2; i++) {
            int r = i * 32 + srow;
            va[i] = *(const bfrag*)(A + (size_t)r * K + k0 + schunk * 8);
            vb[i] = *(const bfrag*)(W + (size_t)(col0 + r) * K + k0 + schunk * 8);
        }
#pragma unroll
        for (int i = 0; i < 2; i++) {
            int r = i * 32 + srow;
            int pc = schunk ^ (r & 7);
            *(bfrag*)(As + r * 128 + pc * 16) = va[i];
            *(bfrag*)(Bs + r * 128 + pc * 16) = vb[i];
        }
        __syncthreads();
#pragma unroll
        for (int s = 0; s < 2; s++) {
            int r = wv * 16 + (lane & 15);
            int ch = (s * 4 + (lane >> 4)) ^ (r & 7);
            bfrag af = *(const bfrag*)(As + r * 128 + ch * 16);
#pragma unroll
            for (int n = 0; n < 4; n++) {
                int r2 = n * 16 + (lane & 15);
                int ch2 = (s * 4 + (lane >> 4)) ^ (r2 & 7);
                bfrag bf = *(const bfrag*)(Bs + r2 * 128 + ch2 * 16);
                acc[n] = __builtin_amdgcn_mfma_f32_16x16x32_bf16(af, bf, acc[n], 0, 0, 0);
            }
        }
        __syncthreads();
    }

    float* Pz = P + (size_t)kz * 64 * N;
#pragma unroll
    for (int n = 0; n < 4; n++) {
        int col = col0 + n * 16 + (lane & 15);
        int rbase = wv * 16 + ((lane >> 4) << 2);
#pragma unroll
        for (int j = 0; j < 4; j++) {
            Pz[(size_t)(rbase + j) * N + col] = acc[n][j];
        }
    }
}

// standalone gemm64k (used for the attn@Weff2 and ws2 GEMMs)
__global__ __launch_bounds__(256) void gemm64k(
    const unsigned short* __restrict__ A, const unsigned short* __restrict__ W,
    float* __restrict__ P, int N, int K, int kc) {
    __shared__ __align__(16) char smem[16384];
    gemm64k_body(A, W, P, N, K, kc, blockIdx.x, blockIdx.y, smem);
}

// logits body (device fn): one 256-thread group per b.
__device__ __forceinline__ void logits_body(
    int b, const float* __restrict__ s_out, const unsigned short* __restrict__ Wh1b,
    const float* __restrict__ bh1, const float* __restrict__ Wh2,
    const float* __restrict__ bh2, float* __restrict__ out, int t, char* smem) {
    float* so = (float*)smem;        // 512
    float* hh = so + 512;            // 512
    float* red = hh + 512;           // 4
    const int tid = threadIdx.x;
    ((float2*)so)[tid] = ((const float2*)(s_out + (size_t)b * CDO))[tid];
    __syncthreads();
#pragma unroll
    for (int p = 0; p < 2; p++) {
        int j = tid + p * 256;
        const unsigned short* w = Wh1b + (size_t)j * CDO;
        float s = bh1[j];
#pragma unroll 4
        for (int k2 = 0; k2 < CDO; k2 += 4) {
            float4 wv = ld4(w + k2);
            s += wv.x * so[k2] + wv.y * so[k2 + 1] + wv.z * so[k2 + 2] + wv.w * so[k2 + 3];
        }
        hh[j] = gelu_exact(s);
    }
    __syncthreads();
    float part = hh[tid] * Wh2[tid] + hh[tid + 256] * Wh2[tid + 256];
#pragma unroll
    for (int off = 32; off; off >>= 1) part += __shfl_down(part, off, 64);
    if ((tid & 63) == 0) red[tid >> 6] = part;
    __syncthreads();
    if (tid == 0) out[b * CT + t] = red[0] + red[1] + red[2] + red[3] + bh2[0];
}

// ---------------------------------------------------------------------------
// mid_kernel: the three independent consumers of sync's outputs in ONE launch.
// blocks 0..127   : qh partials  (s_act @ Weff^T  -> Pq;  16 col x 8 kz)
// blocks 128..383 : zpart        (zb16 @ Ws1a^T   -> P2;  32 col x 8 kz)
// blocks 384..447 : logits       (64 blocks, one per b)
// ---------------------------------------------------------------------------
__global__ __launch_bounds__(256) void mid_kernel(
    const unsigned short* __restrict__ s_act, const unsigned short* __restrict__ weff,
    float* __restrict__ Pq,
    const unsigned short* __restrict__ zb16, const unsigned short* __restrict__ ws1a,
    float* __restrict__ P2,
    const float* __restrict__ s_out, const unsigned short* __restrict__ wh1_b,
    const float* __restrict__ bh1, const float* __restrict__ Wh2,
    const float* __restrict__ bh2, float* __restrict__ out, int t) {
    __shared__ __align__(16) char smem[16384];
    const int blk = blockIdx.x;
    if (blk < 128) {
        gemm64k_body(s_act, weff, Pq, CD, CDA, CDA / 8, blk & 15, blk >> 4, smem);
    } else if (blk < 384) {
        int idx = blk - 128;
        gemm64k_body(zb16, ws1a, P2, 2 * CD, CD, CD / 8, idx & 31, idx >> 5, smem);
    } else {
        logits_body(blk - 384, s_out, wh1_b, bh1, Wh2, bh2, out, t, smem);
    }
}

// LayerNorm + GELU, in place on bf16 h rows.
__global__ __launch_bounds__(256) void ln_gelu_kernel(
    unsigned short* __restrict__ hc, const float* __restrict__ g,
    const float* __restrict__ bb) {
    __shared__ float sred[4];
    const int tid = threadIdx.x;
    size_t base = (size_t)blockIdx.x * CD;
    float4 x = ld4(hc + base + tid * 4);
    float s = x.x + x.y + x.z + x.w;
#pragma unroll
    for (int off = 32; off; off >>= 1) s += __shfl_down(s, off, 64);
    if ((tid & 63) == 0) sred[tid >> 6] = s;
    __syncthreads();
    float mu = (sred[0] + sred[1] + sred[2] + sred[3]) * (1.0f / 1024.0f);
    float d0 = x.x - mu, d1 = x.y - mu, d2 = x.z - mu, d3 = x.w - mu;
    float sq = d0 * d0 + d1 * d1 + d2 * d2 + d3 * d3;
    __syncthreads();
#pragma unroll
    for (int off = 32; off; off >>= 1) sq += __shfl_down(sq, off, 64);
    if ((tid & 63) == 0) sred[tid >> 6] = sq;
    __syncthreads();
    float var = (sred[0] + sred[1] + sred[2] + sred[3]) * (1.0f / 1024.0f);
    float rs = 1.0f / sqrtf(var + 1e-5f);
    float4 gv = ((const float4*)g)[tid];
    float4 bv = ((const float4*)bb)[tid];
    float4 o;
    o.x = gelu_exact(d0 * rs * gv.x + bv.x);
    o.y = gelu_exact(d1 * rs * gv.y + bv.y);
    o.z = gelu_exact(d2 * rs * gv.z + bv.z);
    o.w = gelu_exact(d3 * rs * gv.w + bv.w);
    st4(hc + base + tid * 4, o);
}

// zbufT[b][d][ts]: ts=0 -> z_init[d], else 0; hist = broadcast hist_init.
__global__ __launch_bounds__(256) void init_kernel(
    const float* __restrict__ z_init, const float* __restrict__ hist_init,
    float* __restrict__ zbufT, float* __restrict__ hist) {
    int i = blockIdx.x * 256 + threadIdx.x;
    if (i < CB * CD * CTP1) {
        int rem = i % (CD * CTP1);
        int d = rem / CTP1;
        int ts = rem - d * CTP1;
        zbufT[i] = (ts == 0) ? z_init[d] : 0.0f;
    }
    if (i < CB * CD * CM) {
        hist[i] = hist_init[i % (CD * CM)];
    }
}

// sync: s_act(bf16), s_out(fp32), zb16(bf16 z snapshot) for step t.
__global__ __launch_bounds__(256) void sync_kernel(
    const float* __restrict__ zbufT,
    const float* __restrict__ decay_a, const float* __restrict__ decay_o,
    const int* __restrict__ iia, const int* __restrict__ jja,
    const int* __restrict__ iio, const int* __restrict__ jjo,
    unsigned short* __restrict__ s_act, float* __restrict__ s_out,
    unsigned short* __restrict__ zb16, int t) {
    int b = blockIdx.x >> 2;
    int sg = ((blockIdx.x & 3) << 8) + threadIdx.x;  // 0..1023
    const float* zbT = zbufT + (size_t)b * CD * CTP1;
    zb16[b * CD + sg] = f2us(zbT[(size_t)sg * CTP1 + t]);
    float soft;
    int ii, jj;
    if (sg < CDA) {
        soft = softplusf(decay_a[sg]);
        ii = iia[sg]; jj = jja[sg];
    } else {
        int s2 = sg - CDA;
        soft = softplusf(decay_o[s2]);
        ii = iio[s2]; jj = jjo[s2];
    }
    const float* zi = zbT + (size_t)ii * CTP1;
    const float* zj = zbT + (size_t)jj * CTP1;
    float num = 0.0f, den = 0.0f;
    for (int ts = 0; ts <= t; ts++) {
        float w = expf(-soft * (float)(t - ts));
        num += zi[ts] * zj[ts] * w;
        den += w * w;
    }
    float val = num / sqrtf(den + 1e-8f);
    if (sg < CDA) s_act[b * CDA + sg] = f2us(val);
    else s_out[b * CDO + (sg - CDA)] = val;
}

// ---------------------------------------------------------------------------
// Attention, one (b,h) pair per 512-thread block. r8-verified coalesced
// double-buffered LDS streaming; qh assembled from K-split partials (Pq+beff).
// smem carve (43648 B): buf0 [0,18432) buf1 [18432,36864) att [36864,38912)
// qv [38912,39424) pacc [39424,41472) ppv [41472,43520) red [43520,43584)
// ---------------------------------------------------------------------------
__global__ __launch_bounds__(512) void attn512_kernel(
    const float* __restrict__ Pq, const float* __restrict__ beff,
    const unsigned short* __restrict__ kb, const unsigned short* __restrict__ vT,
    unsigned short* __restrict__ attn_out) {
    __shared__ __align__(16) char smraw[43648];
    char* buf0 = smraw;
    char* buf1 = smraw + 18432;
    float* att  = (float*)(smraw + 36864);
    float* qv   = (float*)(smraw + 38912);
    float* pacc = (float*)(smraw + 39424);
    float* ppv  = (float*)(smraw + 41472);
    float* red  = (float*)(smraw + 43520);
    const int tid = threadIdx.x;
    const int lane = tid & 63;
    const int wv = tid >> 6;
    const int pair = blockIdx.x;
    const int b = pair >> 3, h = pair & 7;
    const float scale = 0.08838834764831845f;  // 1/sqrt(128)

    if (tid < CDH) {
        int col = h * CDH + tid;
        float q = beff[col];
#pragma unroll
        for (int z = 0; z < 8; z++) q += Pq[((size_t)(z * 64 + b)) * CD + col];
        qv[tid] = q;
    }

    // ---- QK^T over 8 chunks of [64 s][128 d] (rows padded to 272 B) ----
    const unsigned short* kbase = kb + (size_t)(b * CS) * CD + h * CDH;
    const int sR0 = tid >> 4, c16 = tid & 15;   // stage: 16 thr/row
    {
        bfrag a = *(const bfrag*)(kbase + (size_t)sR0 * CD + c16 * 8);
        bfrag bb = *(const bfrag*)(kbase + (size_t)(sR0 + 32) * CD + c16 * 8);
        *(bfrag*)(buf0 + sR0 * 272 + c16 * 16) = a;
        *(bfrag*)(buf0 + (sR0 + 32) * 272 + c16 * 16) = bb;
    }
    __syncthreads();
    const int sC = tid & 63, g = wv;            // compute: thread (s, d-group)
    for (int c = 0; c < 8; c++) {
        char* cur = (c & 1) ? buf1 : buf0;
        char* nxt = (c & 1) ? buf0 : buf1;
        bfrag pa, pb;
        if (c < 7) {
            pa = *(const bfrag*)(kbase + (size_t)((c + 1) * 64 + sR0) * CD + c16 * 8);
            pb = *(const bfrag*)(kbase + (size_t)((c + 1) * 64 + sR0 + 32) * CD + c16 * 8);
        }
        {
            bfrag k0 = *(const bfrag*)(cur + sC * 272 + g * 32);
            bfrag k1 = *(const bfrag*)(cur + sC * 272 + g * 32 + 16);
            float s = 0.0f;
#pragma unroll
            for (int e = 0; e < 8; e++) {
                s += us2f((unsigned short)k0[e]) * qv[g * 16 + e];
                s += us2f((unsigned short)k1[e]) * qv[g * 16 + 8 + e];
            }
            pacc[g * 64 + sC] = s;
        }
        __syncthreads();
        if (c < 7) {
            *(bfrag*)(nxt + sR0 * 272 + c16 * 16) = pa;
            *(bfrag*)(nxt + (sR0 + 32) * 272 + c16 * 16) = pb;
        }
        if (tid < 64) {
            float s = 0.0f;
#pragma unroll
            for (int gg = 0; gg < 8; gg++) s += pacc[gg * 64 + tid];
            att[c * 64 + tid] = s * scale;
        }
        __syncthreads();
    }

    // ---- prefetch v chunk 0 while softmax runs ----
    const unsigned short* vbase = vT + (size_t)((b * CNH + h) * CDH) * CS;
    const int dR0 = tid >> 3, c8 = tid & 7;     // stage: 8 thr/row
    bfrag v0a = *(const bfrag*)(vbase + (size_t)dR0 * CS + c8 * 8);
    bfrag v0b = *(const bfrag*)(vbase + (size_t)(dR0 + 64) * CS + c8 * 8);

    // ---- softmax over att[512] (one value per thread) ----
    {
        float v = att[tid];
        float m = v;
#pragma unroll
        for (int o = 32; o; o >>= 1) m = fmaxf(m, __shfl_down(m, o, 64));
        if (lane == 0) red[wv] = m;
        __syncthreads();
        float mx = red[0];
#pragma unroll
        for (int r = 1; r < 8; r++) mx = fmaxf(mx, red[r]);
        float e = expf(v - mx);
        float s = e;
#pragma unroll
        for (int o = 32; o; o >>= 1) s += __shfl_down(s, o, 64);
        __syncthreads();
        if (lane == 0) red[8 + wv] = s;
        __syncthreads();
        float tot = 0.0f;
#pragma unroll
        for (int r = 0; r < 8; r++) tot += red[8 + r];
        att[tid] = e / tot;   // normalized probability
    }
    // write v chunk 0 (buf0 free: last QK compute used buf1)
    *(bfrag*)(buf0 + dR0 * 144 + c8 * 16) = v0a;
    *(bfrag*)(buf0 + (dR0 + 64) * 144 + c8 * 16) = v0b;
    __syncthreads();

    // ---- PV over 8 chunks of [128 d][64 s] (rows padded to 144 B) ----
    const int dC = tid & 127, q = tid >> 7;     // compute: thread (d, s-group)
    float pv = 0.0f;
    for (int c = 0; c < 8; c++) {
        char* cur = (c & 1) ? buf1 : buf0;
        char* nxt = (c & 1) ? buf0 : buf1;
        bfrag pa, pb;
        if (c < 7) {
            pa = *(const bfrag*)(vbase + (size_t)dR0 * CS + (c + 1) * 64 + c8 * 8);
            pb = *(const bfrag*)(vbase + (size_t)(dR0 + 64) * CS + (c + 1) * 64 + c8 * 8);
        }
        {
            bfrag w0 = *(const bfrag*)(cur + dC * 144 + q * 32);
            bfrag w1 = *(const bfrag*)(cur + dC * 144 + q * 32 + 16);
            const float* ap = att + c * 64 + q * 16;
#pragma unroll
            for (int e = 0; e < 8; e++) {
                pv += us2f((unsigned short)w0[e]) * ap[e];
                pv += us2f((unsigned short)w1[e]) * ap[8 + e];
            }
        }
        __syncthreads();
        if (c < 7) {
            *(bfrag*)(nxt + dR0 * 144 + c8 * 16) = pa;
            *(bfrag*)(nxt + (dR0 + 64) * 144 + c8 * 16) = pb;
        }
        __syncthreads();
    }
    ppv[q * 128 + dC] = pv;
    __syncthreads();
    if (tid < CDH) {
        float o = ppv[tid] + ppv[128 + tid] + ppv[256 + tid] + ppv[384 + tid];
        attn_out[(size_t)b * CD + h * CDH + tid] = f2us(o);
    }
}

// pre1 = gelu(sum_z P2 + sum_z P3 + beff1); i over 64x2048.
__global__ __launch_bounds__(256) void pre1r_kernel(
    const float* __restrict__ P2, const float* __restrict__ P3,
    const float* __restrict__ beff1, unsigned short* __restrict__ pre1) {
    int i = blockIdx.x * 256 + threadIdx.x;
    int j = i & 2047;
    float v = beff1[j];
#pragma unroll
    for (int z = 0; z < 8; z++)
        v += P2[(size_t)z * 131072 + i] + P3[(size_t)z * 131072 + i];
    pre1[i] = f2us(gelu_exact(v));
}

// pre = sum_z Pw + bs2, fused neuron MLP -> zbufT[:,:,t+1]; idx over (b,d).
__global__ __launch_bounds__(256) void ws2r_neuron_kernel(
    const float* __restrict__ Pw, const float* __restrict__ bs2,
    float* __restrict__ hist,
    const float* __restrict__ Wn1, const float* __restrict__ bn1,
    const float* __restrict__ Wn2, const float* __restrict__ bn2,
    const float* __restrict__ Wn3, const float* __restrict__ bn3,
    float* __restrict__ zbufT, int t) {
    int idx = blockIdx.x * 256 + threadIdx.x;  // (b,d)
    int d = idx & 1023;
    float prev = bs2[d];
#pragma unroll
    for (int z = 0; z < 8; z++) prev += Pw[(size_t)z * 65536 + idx];
    float hv[CM];
    float* hp = hist + (size_t)idx * CM;
#pragma unroll
    for (int m = 0; m < CM - 1; m++) hv[m] = hp[m + 1];
    hv[CM - 1] = prev;
#pragma unroll
    for (int m = 0; m < CM; m++) hp[m] = hv[m];
    float x1[CH];
#pragma unroll
    for (int hh = 0; hh < CH; hh++) {
        const float* w = Wn1 + ((size_t)d * CH + hh) * CM;
        float s = bn1[d * CH + hh];
#pragma unroll
        for (int m = 0; m < CM; m++) s += hv[m] * w[m];
        x1[hh] = gelu_exact(s);
    }
    float x2[CH];
#pragma unroll
    for (int g = 0; g < CH; g++) {
        float s = bn2[d * CH + g];
#pragma unroll
        for (int hh = 0; hh < CH; hh++) s += x1[hh] * Wn2[((size_t)d * CH + g) * CH + hh];
        x2[g] = gelu_exact(s);
    }
    float z = bn3[d];
#pragma unroll
    for (int hh = 0; hh < CH; hh++) z += x2[hh] * Wn3[d * CH + hh];
    zbufT[(size_t)idx * CTP1 + (t + 1)] = z;
}

// Writes v to all outputs; v encodes ws_size in MB so a failure is decodable.
__global__ void sentinel_kernel(float* out, float v) {
    int i = blockIdx.x * 256 + threadIdx.x;
    if (i < CB * CT) out[i] = v;
}

extern "C" void kernel_launch(void* const* d_in, const int* in_sizes, int n_in,
                              void* d_out, int out_size, void* d_ws, size_t ws_size,
                              hipStream_t stream) {
    const float* emb = (const float*)d_in[0];
    const float* Wp = (const float*)d_in[1];
    const float* bp = (const float*)d_in[2];
    const float* ln_g = (const float*)d_in[3];
    const float* ln_b = (const float*)d_in[4];
    const float* decay_a = (const float*)d_in[5];
    const float* decay_o = (const float*)d_in[6];
    const float* Wq = (const float*)d_in[7];
    const float* bq = (const float*)d_in[8];
    const float* Wqkv = (const float*)d_in[9];
    const float* bqkv = (const float*)d_in[10];
    const float* Wo = (const float*)d_in[11];
    const float* bo = (const float*)d_in[12];
    const float* Ws1 = (const float*)d_in[13];
    const float* bs1 = (const float*)d_in[14];
    const float* Ws2 = (const float*)d_in[15];
    const float* bs2 = (const float*)d_in[16];
    const float* Wn1 = (const float*)d_in[17];
    const float* bn1 = (const float*)d_in[18];
    const float* Wn2 = (const float*)d_in[19];
    const float* bn2 = (const float*)d_in[20];
    const float* Wn3 = (const float*)d_in[21];
    const float* bn3 = (const float*)d_in[22];
    const float* Wh1 = (const float*)d_in[23];
    const float* bh1 = (const float*)d_in[24];
    const float* Wh2 = (const float*)d_in[25];
    const float* bh2 = (const float*)d_in[26];
    const float* z_init = (const float*)d_in[27];
    const float* hist_init = (const float*)d_in[28];
    const int* iia = (const int*)d_in[29];
    const int* jja = (const int*)d_in[30];
    const int* iio = (const int*)d_in[31];
    const int* jjo = (const int*)d_in[32];
    float* out = (float*)d_out;

    char* wsb = (char*)d_ws;
    size_t off = 0;
    auto alloc = [&](size_t bytes) {
        void* p = wsb + off;
        off += (bytes + 255) & ~(size_t)255;
        return p;
    };
    unsigned short* ctx  = (unsigned short*)alloc((size_t)CB * CS * CD * 2);  // h/ctx, later vT
    unsigned short* kbuf = (unsigned short*)alloc((size_t)CB * CS * CD * 2);
    unsigned short* vbuf = (unsigned short*)alloc((size_t)CB * CS * CD * 2);
    float* zbufT = (float*)alloc((size_t)CB * CD * CTP1 * 4);
    float* hist = (float*)alloc((size_t)CB * CD * CM * 4);
    unsigned short* s_act = (unsigned short*)alloc((size_t)CB * CDA * 2);
    float* s_out = (float*)alloc((size_t)CB * CDO * 4);
    unsigned short* zb16 = (unsigned short*)alloc((size_t)CB * CD * 2);
    unsigned short* attn_out = (unsigned short*)alloc((size_t)CB * CD * 2);
    unsigned short* pre1 = (unsigned short*)alloc((size_t)CB * 2 * CD * 2);
    // K-split partial buffers (fp32). Pq doubles as Pw (disjoint lifetimes).
    float* Pq = (float*)alloc((size_t)8 * 64 * CD * 4);          // 2 MB
    float* P2 = (float*)alloc((size_t)8 * 64 * 2 * CD * 4);      // 4 MB
    float* P3 = (float*)alloc((size_t)8 * 64 * 2 * CD * 4);      // 4 MB
    // bf16 weights / fused weights
    unsigned short* wqkv_b = (unsigned short*)alloc((size_t)3 * CD * CD * 2);
    unsigned short* ws2_b = (unsigned short*)alloc((size_t)CD * 2 * CD * 2);
    unsigned short* wh1_b = (unsigned short*)alloc((size_t)CDO * CDO * 2);
    unsigned short* wqT_b = (unsigned short*)alloc((size_t)CDA * CD * 2);
    unsigned short* weff_b = (unsigned short*)alloc((size_t)CD * CDA * 2);
    unsigned short* ws1a_b = (unsigned short*)alloc((size_t)2 * CD * CD * 2);
    unsigned short* ws1b_b = (unsigned short*)alloc((size_t)2 * CD * CD * 2);
    unsigned short* woT_b = (unsigned short*)alloc((size_t)CD * CD * 2);
    unsigned short* weff2_b = (unsigned short*)alloc((size_t)2 * CD * CD * 2);
    float* beff = (float*)alloc((size_t)CD * 4);
    float* beff1 = (float*)alloc((size_t)2 * CD * 4);
    float* zbias = (float*)alloc((size_t)2 * CD * 4);
    unsigned short* vT = ctx;  // alias: ctx dead after the v GEMM

    if (off > ws_size) {
        sentinel_kernel<<<dim3(4), dim3(256), 0, stream>>>(out, -(float)(ws_size >> 20));
        return;
    }

    // ---- One-time setup ----
    auto conv = [&](const float* s, unsigned short* d, size_t n) {
        int n4 = (int)(n / 4);
        convert_bf16_kernel<<<dim3((n4 + 255) / 256), 256, 0, stream>>>(s, d, n4);
    };
    conv(Wqkv, wqkv_b, (size_t)3 * CD * CD);
    conv(Ws2, ws2_b, (size_t)CD * 2 * CD);
    conv(Wh1, wh1_b, (size_t)CDO * CDO);
    transpose_wq_kernel<<<dim3((CDA * CD + 255) / 256), 256, 0, stream>>>(Wq, wqT_b);
    transpose_wo_kernel<<<dim3((CD * CD + 255) / 256), 256, 0, stream>>>(Wo, woT_b);
    pack_ws1_kernel<<<dim3((2 * CD * CD + 255) / 256), 256, 0, stream>>>(Ws1, ws1a_b, ws1b_b);
    hipMemsetAsync(zbias, 0, (size_t)2 * CD * 4, stream);
    beff_kernel<<<dim3(4), 256, 0, stream>>>(Wqkv, bq, bqkv, beff);
    beff1_kernel<<<dim3(8), 256, 0, stream>>>(Ws1, bo, bs1, beff1);
    // Weff = Wq3 @ Wq  (1024 x 512, K=1024)
    gemm_mfma<unsigned short, unsigned short><<<dim3(CD / 128, CDA / 128), 256, 0, stream>>>(
        wqkv_b, wqT_b, zbias, weff_b, CDA, CD);
    // Weff2 = Ws1b @ Wo  (2048 x 1024, K=1024)
    gemm_mfma<unsigned short, unsigned short><<<dim3(2 * CD / 128, CD / 128), 256, 0, stream>>>(
        ws1b_b, woT_b, zbias, weff2_b, CD, CD);

    // ---- Phase A ----
    gemm_mfma<float, float><<<dim3(CB * CS / 128, CD / 128), 256, 0, stream>>>(
        emb, Wp, bp, ctx, CD, CDE);
    ln_gelu_kernel<<<dim3(CB * CS), 256, 0, stream>>>(ctx, ln_g, ln_b);
    gemm_mfma<unsigned short, unsigned short><<<dim3(CB * CS / 128, CD / 128), 256, 0, stream>>>(
        ctx, wqkv_b + (size_t)CD * CD, bqkv + CD, kbuf, CD, CD);
    gemm_mfma<unsigned short, unsigned short><<<dim3(CB * CS / 128, CD / 128), 256, 0, stream>>>(
        ctx, wqkv_b + (size_t)2 * CD * CD, bqkv + 2 * CD, vbuf, CD, CD);
    // vT[b][h][d][s] (aliases ctx — ctx is dead now)
    transpose_v_kernel<<<dim3(CB * CNH * 16), 256, 0, stream>>>(vbuf, vT);
    init_kernel<<<dim3(4352), 256, 0, stream>>>(z_init, hist_init, zbufT, hist);

    // ---- Phase B: 16 steps, 6 launches each ----
    for (int t = 0; t < CT; t++) {
        sync_kernel<<<dim3(256), 256, 0, stream>>>(
            zbufT, decay_a, decay_o, iia, jja, iio, jjo, s_act, s_out, zb16, t);
        // qh partials + zpart partials + logits in ONE launch
        mid_kernel<<<dim3(448), 256, 0, stream>>>(
            s_act, weff_b, Pq, zb16, ws1a_b, P2, s_out, wh1_b, bh1, Wh2, bh2, out, t);
        // attention (sums Pq internally)
        attn512_kernel<<<dim3(CB * CNH), 512, 0, stream>>>(Pq, beff, kbuf, vT, attn_out);
        // attn @ Weff2^T partials (N=2048, K=1024)
        gemm64k<<<dim3(32, 8), 256, 0, stream>>>(attn_out, weff2_b, P3, 2 * CD, CD, CD / 8);
        // pre1 = gelu(zpart + attnpart + beff1)
        pre1r_kernel<<<dim3(512), 256, 0, stream>>>(P2, P3, beff1, pre1);
        // ws2 partials: pre1 @ Ws2^T (N=1024, K=2048); Pw aliases Pq
        gemm64k<<<dim3(16, 8), 256, 0, stream>>>(pre1, ws2_b, Pq, CD, 2 * CD, 2 * CD / 8);
        // pre reduce + neuron MLP -> zbufT[:,:,t+1]
        ws2r_neuron_kernel<<<dim3(256), 256, 0, stream>>>(
            Pq, bs2, hist, Wn1, bn1, Wn2, bn2, Wn3, bn3, zbufT, t);
    }
}